// Round 1
// baseline (1371.330 us; speedup 1.0000x reference)
//
#include <hip/hip_runtime.h>

#define N_NODES 45000
#define F_NNZ   33
#define B_BATCH 64
#define H_DIM   64
#define C_OUT   10
#define NUM_STEPS 30

// Transpose x (B,N) -> xT (N,B) and write g0 = 2*xT (since h0 = x, first step input is x + h0 = 2x)
__global__ __launch_bounds__(256) void transpose_init(const float* __restrict__ x,
                                                      float* __restrict__ xT,
                                                      float* __restrict__ g0) {
    __shared__ float tile[64][65];
    int n0  = blockIdx.x * 64;
    int t   = threadIdx.x;
    int ln  = t & 63;   // phase1: n-offset within tile; phase2: b
    int sub = t >> 6;   // 0..3
    // phase 1: coalesced reads along n
    for (int bb = 0; bb < 16; ++bb) {
        int b = bb * 4 + sub;
        int n = n0 + ln;
        float v = (n < N_NODES) ? x[(size_t)b * N_NODES + n] : 0.f;
        tile[ln][b] = v;
    }
    __syncthreads();
    // phase 2: coalesced writes along b
    for (int nn = 0; nn < 16; ++nn) {
        int nrel = nn * 4 + sub;
        int n = n0 + nrel;
        if (n < N_NODES) {
            float v = tile[nrel][ln];
            xT[(size_t)n * 64 + ln] = v;
            g0[(size_t)n * 64 + ln] = 2.f * v;
        }
    }
}

// One wave per row n. g layout (N, 64): gather of row j = one coalesced 256B load.
__global__ __launch_bounds__(256) void step_kernel(const float* __restrict__ gIn,
                                                   const float* __restrict__ xT,
                                                   const float* __restrict__ values,
                                                   const float* __restrict__ bias,
                                                   const int*   __restrict__ idx,
                                                   float* __restrict__ gOut,
                                                   int addX) {
    int wid  = threadIdx.x >> 6;
    int lane = threadIdx.x & 63;
    int n = __builtin_amdgcn_readfirstlane((int)blockIdx.x * 4 + wid);  // wave-uniform -> scalar loads
    const int*   ip = idx    + (size_t)n * F_NNZ;
    const float* vp = values + (size_t)n * F_NNZ;
    float acc = 0.f;
#pragma unroll
    for (int f = 0; f < F_NNZ; ++f) {
        int   j = ip[f];
        float v = vp[f];
        acc = fmaf(v, gIn[(size_t)j * 64 + lane], acc);
    }
    float tv = fmaxf(acc + bias[n], 0.f);
    size_t o = (size_t)n * 64 + lane;
    gOut[o] = addX ? (xT[o] + tv) : tv;
}

// Split-K partial GEMM: hid[b][h] += sum_{n in chunk} hT[n][b] * w1[n][h]
__global__ __launch_bounds__(256) void head_partial(const float* __restrict__ hT,
                                                    const float* __restrict__ w1,
                                                    float* __restrict__ hidAcc) {
    int h    = threadIdx.x & 63;
    int brel = threadIdx.x >> 6;
    int b    = blockIdx.y * 4 + brel;
    int n0   = blockIdx.x * 1000;
    float acc = 0.f;
    for (int i = 0; i < 1000; ++i) {
        int n = n0 + i;
        acc = fmaf(hT[(size_t)n * 64 + b], w1[(size_t)n * 64 + h], acc);
    }
    atomicAdd(&hidAcc[b * 64 + h], acc);
}

// out[b][c] = b2[c] + sum_h relu(hidAcc[b][h] + b1[h]) * w2[h][c]
__global__ __launch_bounds__(1024) void head_final(const float* __restrict__ hidAcc,
                                                   const float* __restrict__ b1,
                                                   const float* __restrict__ w2,
                                                   const float* __restrict__ b2,
                                                   float* __restrict__ out) {
    int t = threadIdx.x;
    if (t >= B_BATCH * C_OUT) return;
    int b = t / C_OUT, c = t % C_OUT;
    float acc = b2[c];
#pragma unroll
    for (int h = 0; h < H_DIM; ++h) {
        float hv = fmaxf(hidAcc[b * 64 + h] + b1[h], 0.f);
        acc = fmaf(hv, w2[h * C_OUT + c], acc);
    }
    out[t] = acc;
}

extern "C" void kernel_launch(void* const* d_in, const int* in_sizes, int n_in,
                              void* d_out, int out_size, void* d_ws, size_t ws_size,
                              hipStream_t stream) {
    const float* x      = (const float*)d_in[0];
    const float* values = (const float*)d_in[1];
    const float* bias   = (const float*)d_in[2];
    const float* w1     = (const float*)d_in[3];
    const float* b1     = (const float*)d_in[4];
    const float* w2     = (const float*)d_in[5];
    const float* b2     = (const float*)d_in[6];
    const int*   idx    = (const int*)d_in[7];
    float* out = (float*)d_out;

    size_t per = (size_t)N_NODES * 64;
    float* xT     = (float*)d_ws;
    float* gA     = xT + per;
    float* gB     = gA + per;
    float* hidAcc = gB + per;

    hipMemsetAsync(hidAcc, 0, B_BATCH * H_DIM * sizeof(float), stream);
    transpose_init<<<(N_NODES + 63) / 64, 256, 0, stream>>>(x, xT, gA);

    const float* gin = gA;
    float*       gout = gB;
    for (int s = 0; s < NUM_STEPS; ++s) {
        int addX = (s < NUM_STEPS - 1) ? 1 : 0;
        step_kernel<<<N_NODES / 4, 256, 0, stream>>>(gin, xT, values, bias, idx, gout, addX);
        float* tmp = (float*)gin; gin = gout; gout = tmp;
    }
    // gin now holds pure h (step 30 wrote relu(...) without +x)

    head_partial<<<dim3(45, 16), 256, 0, stream>>>(gin, w1, hidAcc);
    head_final<<<1, 1024, 0, stream>>>(hidAcc, b1, w2, b2, out);
}

// Round 2
// 974.310 us; speedup vs baseline: 1.4075x; 1.4075x over previous
//
#include <hip/hip_runtime.h>
#include <hip/hip_bf16.h>

#define N_NODES 45000
#define F_NNZ   33
#define B_BATCH 64
#define H_DIM   64
#define C_OUT   10
#define NUM_STEPS 30
#define HCHUNK  250
#define NCHUNKS (N_NODES / HCHUNK)   // 180

__device__ inline float bf2f(unsigned short u) {
    return __uint_as_float(((unsigned int)u) << 16);
}
__device__ inline unsigned short f2bf(float f) {
    unsigned int x = __float_as_uint(f);
    unsigned int r = (x + 0x7fffu + ((x >> 16) & 1u)) >> 16;   // round-to-nearest-even
    return (unsigned short)r;
}

// Transpose x (B,N) -> xT (N,B) fp32, and g0 = bf16(2*x) (h0 = x, first step input = x + h0)
__global__ __launch_bounds__(256) void transpose_init(const float* __restrict__ x,
                                                      float* __restrict__ xT,
                                                      unsigned short* __restrict__ g0) {
    __shared__ float tile[64][65];
    int n0  = blockIdx.x * 64;
    int t   = threadIdx.x;
    int ln  = t & 63;
    int sub = t >> 6;
    for (int bb = 0; bb < 16; ++bb) {
        int b = bb * 4 + sub;
        int n = n0 + ln;
        float v = (n < N_NODES) ? x[(size_t)b * N_NODES + n] : 0.f;
        tile[ln][b] = v;
    }
    __syncthreads();
    for (int nn = 0; nn < 16; ++nn) {
        int nrel = nn * 4 + sub;
        int n = n0 + nrel;
        if (n < N_NODES) {
            float v = tile[nrel][ln];
            xT[(size_t)n * 64 + ln] = v;
            g0[(size_t)n * 64 + ln] = f2bf(2.f * v);
        }
    }
}

// One wave per row n. g layout (N, 64) bf16: gather of row j = one coalesced 128B load.
__global__ __launch_bounds__(256) void step_kernel(const unsigned short* __restrict__ gIn,
                                                   const float* __restrict__ xT,
                                                   const float* __restrict__ values,
                                                   const float* __restrict__ bias,
                                                   const int*   __restrict__ idx,
                                                   unsigned short* __restrict__ gOut,
                                                   int addX) {
    int wid  = threadIdx.x >> 6;
    int lane = threadIdx.x & 63;
    int n = __builtin_amdgcn_readfirstlane((int)blockIdx.x * 4 + wid);  // wave-uniform -> scalar loads
    const int*   ip = idx    + (size_t)n * F_NNZ;
    const float* vp = values + (size_t)n * F_NNZ;
    float acc = 0.f;
#pragma unroll
    for (int f = 0; f < F_NNZ; ++f) {
        int   j = ip[f];
        float v = vp[f];
        acc = fmaf(v, bf2f(gIn[(size_t)j * 64 + lane]), acc);
    }
    float tv = fmaxf(acc + bias[n], 0.f);
    size_t o = (size_t)n * 64 + lane;
    float ov = addX ? (xT[o] + tv) : tv;
    gOut[o] = f2bf(ov);
}

// One-pass K-chunked head GEMM: block = chunk of HCHUNK rows, computes all 64x64 partials.
// Wave w owns b in [w*16, w*16+16), lane = h. w1 row coalesced; hT row broadcast (uniform).
__global__ __launch_bounds__(256) void head_partial2(const unsigned short* __restrict__ hT,
                                                     const float* __restrict__ w1,
                                                     float* __restrict__ partial) {
    int lane = threadIdx.x & 63;   // h
    int w    = threadIdx.x >> 6;   // b-group 0..3
    int n0   = blockIdx.x * HCHUNK;
    float acc[16];
#pragma unroll
    for (int k = 0; k < 16; ++k) acc[k] = 0.f;
    for (int i = 0; i < HCHUNK; ++i) {
        int n = n0 + i;
        float wv = w1[(size_t)n * 64 + lane];
        const unsigned short* hrow = hT + (size_t)n * 64 + w * 16;
#pragma unroll
        for (int k = 0; k < 16; ++k) {
            acc[k] = fmaf(bf2f(hrow[k]), wv, acc[k]);
        }
    }
    float* p = partial + (size_t)blockIdx.x * 4096 + (size_t)(w * 16) * 64 + lane;
#pragma unroll
    for (int k = 0; k < 16; ++k) p[(size_t)k * 64] = acc[k];
}

// hidAcc[t] = sum over chunks of partial[chunk][t], t in [0,4096)
__global__ __launch_bounds__(256) void head_reduce(const float* __restrict__ partial,
                                                   float* __restrict__ hidAcc) {
    int t = blockIdx.x * 256 + threadIdx.x;
    float acc = 0.f;
    for (int i = 0; i < NCHUNKS; ++i) acc += partial[(size_t)i * 4096 + t];
    hidAcc[t] = acc;
}

// out[b][c] = b2[c] + sum_h relu(hidAcc[b][h] + b1[h]) * w2[h][c]
__global__ __launch_bounds__(1024) void head_final(const float* __restrict__ hidAcc,
                                                   const float* __restrict__ b1,
                                                   const float* __restrict__ w2,
                                                   const float* __restrict__ b2,
                                                   float* __restrict__ out) {
    int t = threadIdx.x;
    if (t >= B_BATCH * C_OUT) return;
    int b = t / C_OUT, c = t % C_OUT;
    float acc = b2[c];
#pragma unroll
    for (int h = 0; h < H_DIM; ++h) {
        float hv = fmaxf(hidAcc[b * 64 + h] + b1[h], 0.f);
        acc = fmaf(hv, w2[h * C_OUT + c], acc);
    }
    out[t] = acc;
}

extern "C" void kernel_launch(void* const* d_in, const int* in_sizes, int n_in,
                              void* d_out, int out_size, void* d_ws, size_t ws_size,
                              hipStream_t stream) {
    const float* x      = (const float*)d_in[0];
    const float* values = (const float*)d_in[1];
    const float* bias   = (const float*)d_in[2];
    const float* w1     = (const float*)d_in[3];
    const float* b1     = (const float*)d_in[4];
    const float* w2     = (const float*)d_in[5];
    const float* b2     = (const float*)d_in[6];
    const int*   idx    = (const int*)d_in[7];
    float* out = (float*)d_out;

    size_t per = (size_t)N_NODES * 64;
    float*          xT      = (float*)d_ws;
    unsigned short* gA      = (unsigned short*)(xT + per);
    unsigned short* gB      = gA + per;
    float*          partial = (float*)(gB + per);          // NCHUNKS * 4096 floats
    float*          hidAcc  = partial + (size_t)NCHUNKS * 4096;

    transpose_init<<<(N_NODES + 63) / 64, 256, 0, stream>>>(x, xT, gA);

    const unsigned short* gin  = gA;
    unsigned short*       gout = gB;
    for (int s = 0; s < NUM_STEPS; ++s) {
        int addX = (s < NUM_STEPS - 1) ? 1 : 0;
        step_kernel<<<N_NODES / 4, 256, 0, stream>>>(gin, xT, values, bias, idx, gout, addX);
        unsigned short* tmp = (unsigned short*)gin; gin = gout; gout = tmp;
    }
    // gin now holds pure h (final step wrote relu(...) without +x)

    head_partial2<<<NCHUNKS, 256, 0, stream>>>(gin, w1, partial);
    head_reduce<<<16, 256, 0, stream>>>(partial, hidAcc);
    head_final<<<1, 1024, 0, stream>>>(hidAcc, b1, w2, b2, out);
}

// Round 3
// 929.968 us; speedup vs baseline: 1.4746x; 1.0477x over previous
//
#include <hip/hip_runtime.h>

#define N_NODES 45000
#define F_NNZ   33
#define NUM_STEPS 30
#define HCHUNK  50
#define NHEADBLK (N_NODES / HCHUNK)   // 900

__device__ inline float bf2f(unsigned short u) {
    return __uint_as_float(((unsigned int)u) << 16);
}
__device__ inline unsigned short f2bf(float f) {
    unsigned int x = __float_as_uint(f);
    unsigned int r = (x + 0x7fffu + ((x >> 16) & 1u)) >> 16;   // RNE
    return (unsigned short)r;
}

// pk[t] = (bf16(values[t]) << 16) | u16(idx[t])   — 4 B per nnz entry
__global__ __launch_bounds__(256) void pack_kernel(const int* __restrict__ idx,
                                                   const float* __restrict__ values,
                                                   unsigned int* __restrict__ pk) {
    int t = blockIdx.x * 256 + threadIdx.x;
    if (t >= N_NODES * F_NNZ) return;
    unsigned int vb = f2bf(values[t]);
    pk[t] = (vb << 16) | (unsigned int)idx[t];
}

// x (B=64, N) -> split transposed halves: xT{0,1} fp32 (N,32), g0{0,1} = bf16(2x)
__global__ __launch_bounds__(256) void transpose_init(const float* __restrict__ x,
                                                      float* __restrict__ xT0,
                                                      float* __restrict__ xT1,
                                                      unsigned short* __restrict__ g0,
                                                      unsigned short* __restrict__ g1) {
    __shared__ float tile[64][65];
    int n0  = blockIdx.x * 64;
    int t   = threadIdx.x;
    int ln  = t & 63;
    int sub = t >> 6;
    for (int bb = 0; bb < 16; ++bb) {
        int b = bb * 4 + sub;
        int n = n0 + ln;
        float v = (n < N_NODES) ? x[(size_t)b * N_NODES + n] : 0.f;
        tile[ln][b] = v;
    }
    __syncthreads();
    for (int nn = 0; nn < 16; ++nn) {
        int nrel = nn * 4 + sub;
        int n = n0 + nrel;
        if (n < N_NODES) {
            float v = tile[nrel][ln];         // ln = b
            int half = ln >> 5, l32 = ln & 31;
            size_t pos = (size_t)n * 32 + l32;
            (half ? xT1 : xT0)[pos] = v;
            (half ? g1 : g0)[pos] = f2bf(2.f * v);
        }
    }
}

// One half-batch (32 b's) step. Wave = 2 rows (lanes 0-31 row n0, 32-63 row n0+1).
// g (N,32) bf16 = 2.88 MB -> L2-resident. pk scalar-loaded. xT nt-load, gOut nt-store.
__global__ __launch_bounds__(256) void step_half(const unsigned short* __restrict__ gIn,
                                                 const float* __restrict__ xT,
                                                 const unsigned int* __restrict__ pk,
                                                 const float* __restrict__ bias,
                                                 unsigned short* __restrict__ gOut,
                                                 int addX) {
    int wid  = threadIdx.x >> 6;
    int lane = threadIdx.x & 63;
    int n0 = __builtin_amdgcn_readfirstlane((int)blockIdx.x * 8 + wid * 2);
    int rowsel = lane >> 5;
    int l32    = lane & 31;
    const unsigned int* p = pk + (size_t)n0 * F_NNZ;   // rows n0, n0+1 contiguous: 66 dwords
    float acc = 0.f;
#pragma unroll
    for (int f = 0; f < F_NNZ; ++f) {
        unsigned int e0 = p[f];            // scalar load (wave-uniform)
        unsigned int e1 = p[f + F_NNZ];
        unsigned int e  = rowsel ? e1 : e0;
        int   j = (int)(e & 0xffffu);
        float v = __uint_as_float(e & 0xffff0000u);    // bf16 value in high bits
        acc = fmaf(v, bf2f(gIn[(size_t)j * 32 + l32]), acc);
    }
    int n = n0 + rowsel;
    float tv = fmaxf(acc + bias[n], 0.f);
    size_t o = (size_t)n * 32 + l32;
    float ov = tv;
    if (addX) ov += __builtin_nontemporal_load(&xT[o]);
    __builtin_nontemporal_store(f2bf(ov), &gOut[o]);
}

// One-pass head GEMM chunk with atomic accumulate: hid[b][h] += sum_n h[b][n]*w1[n][h]
__global__ __launch_bounds__(256) void head_partial3(const unsigned short* __restrict__ h0,
                                                     const unsigned short* __restrict__ h1,
                                                     const float* __restrict__ w1,
                                                     float* __restrict__ hidAcc) {
    int lane = threadIdx.x & 63;   // h
    int w    = threadIdx.x >> 6;   // b-group of 16: b = w*16+k
    const unsigned short* hh = (w >> 1) ? h1 : h0;
    int boff = (w & 1) * 16;       // offset within the 32-wide half
    int n0   = blockIdx.x * HCHUNK;
    float acc[16];
#pragma unroll
    for (int k = 0; k < 16; ++k) acc[k] = 0.f;
    for (int i = 0; i < HCHUNK; ++i) {
        int n = n0 + i;
        float wv = w1[(size_t)n * 64 + lane];
        const unsigned short* hrow = hh + (size_t)n * 32 + boff;
#pragma unroll
        for (int k = 0; k < 16; ++k)
            acc[k] = fmaf(bf2f(hrow[k]), wv, acc[k]);
    }
#pragma unroll
    for (int k = 0; k < 16; ++k) {
        int b = w * 16 + k;
        atomicAdd(&hidAcc[b * 64 + lane], acc[k]);
    }
}

// out[b][c] = b2[c] + sum_h relu(hidAcc[b][h] + b1[h]) * w2[h][c]
__global__ __launch_bounds__(1024) void head_final(const float* __restrict__ hidAcc,
                                                   const float* __restrict__ b1,
                                                   const float* __restrict__ w2,
                                                   const float* __restrict__ b2,
                                                   float* __restrict__ out) {
    int t = threadIdx.x;
    if (t >= 640) return;
    int b = t / 10, c = t % 10;
    float acc = b2[c];
#pragma unroll
    for (int h = 0; h < 64; ++h) {
        float hv = fmaxf(hidAcc[b * 64 + h] + b1[h], 0.f);
        acc = fmaf(hv, w2[h * 10 + c], acc);
    }
    out[t] = acc;
}

extern "C" void kernel_launch(void* const* d_in, const int* in_sizes, int n_in,
                              void* d_out, int out_size, void* d_ws, size_t ws_size,
                              hipStream_t stream) {
    const float* x      = (const float*)d_in[0];
    const float* values = (const float*)d_in[1];
    const float* bias   = (const float*)d_in[2];
    const float* w1     = (const float*)d_in[3];
    const float* b1     = (const float*)d_in[4];
    const float* w2     = (const float*)d_in[5];
    const float* b2     = (const float*)d_in[6];
    const int*   idx    = (const int*)d_in[7];
    float* out = (float*)d_out;

    size_t perHalfF = (size_t)N_NODES * 32;            // floats / shorts per half
    float*          xT0 = (float*)d_ws;                //  5.76 MB
    float*          xT1 = xT0 + perHalfF;              //  5.76 MB
    unsigned short* gA0 = (unsigned short*)(xT1 + perHalfF);   // 2.88 MB each
    unsigned short* gB0 = gA0 + perHalfF;
    unsigned short* gA1 = gB0 + perHalfF;
    unsigned short* gB1 = gA1 + perHalfF;
    unsigned int*   pk  = (unsigned int*)(gB1 + perHalfF);     // 5.94 MB
    float*          hidAcc = (float*)(pk + (size_t)N_NODES * F_NNZ);   // 16 KB

    hipMemsetAsync(hidAcc, 0, 64 * 64 * sizeof(float), stream);
    pack_kernel<<<(N_NODES * F_NNZ + 255) / 256, 256, 0, stream>>>(idx, values, pk);
    transpose_init<<<(N_NODES + 63) / 64, 256, 0, stream>>>(x, xT0, xT1, gA0, gA1);

    const unsigned short* gin0 = gA0; unsigned short* gout0 = gB0;
    const unsigned short* gin1 = gA1; unsigned short* gout1 = gB1;
    for (int s = 0; s < NUM_STEPS; ++s) {
        int addX = (s < NUM_STEPS - 1) ? 1 : 0;
        step_half<<<N_NODES / 8, 256, 0, stream>>>(gin0, xT0, pk, bias, gout0, addX);
        step_half<<<N_NODES / 8, 256, 0, stream>>>(gin1, xT1, pk, bias, gout1, addX);
        unsigned short* t0 = (unsigned short*)gin0; gin0 = gout0; gout0 = t0;
        unsigned short* t1 = (unsigned short*)gin1; gin1 = gout1; gout1 = t1;
    }

    head_partial3<<<NHEADBLK, 256, 0, stream>>>(gin0, gin1, w1, hidAcc);
    head_final<<<1, 1024, 0, stream>>>(hidAcc, b1, w2, b2, out);
}

// Round 5
// 850.832 us; speedup vs baseline: 1.6118x; 1.0930x over previous
//
#include <hip/hip_runtime.h>

#define N_NODES 45000
#define F_NNZ   33
#define NUM_STEPS 30
#define HCHUNK  100
#define NHEADBLK (N_NODES / HCHUNK)   // 450

__device__ inline float bf2f(unsigned short u) {
    return __uint_as_float(((unsigned int)u) << 16);
}
__device__ inline unsigned short f2bf(float f) {
    unsigned int x = __float_as_uint(f);
    unsigned int r = (x + 0x7fffu + ((x >> 16) & 1u)) >> 16;   // RNE
    return (unsigned short)r;
}

// pk[t] = (bf16(values[t]) << 16) | u16(idx[t])   — 4 B per nnz entry
__global__ __launch_bounds__(256) void pack_kernel(const int* __restrict__ idx,
                                                   const float* __restrict__ values,
                                                   unsigned int* __restrict__ pk) {
    int t = blockIdx.x * 256 + threadIdx.x;
    if (t >= N_NODES * F_NNZ) return;
    unsigned int vb = f2bf(values[t]);
    pk[t] = (vb << 16) | (unsigned int)idx[t];
}

// x (B=64, N) -> split transposed halves: xT{0,1} fp32 (N,32), g0{0,1} = bf16(2x)
__global__ __launch_bounds__(256) void transpose_init(const float* __restrict__ x,
                                                      float* __restrict__ xT0,
                                                      float* __restrict__ xT1,
                                                      unsigned short* __restrict__ g0,
                                                      unsigned short* __restrict__ g1) {
    __shared__ float tile[64][65];
    int n0  = blockIdx.x * 64;
    int t   = threadIdx.x;
    int ln  = t & 63;
    int sub = t >> 6;
    for (int bb = 0; bb < 16; ++bb) {
        int b = bb * 4 + sub;
        int n = n0 + ln;
        float v = (n < N_NODES) ? x[(size_t)b * N_NODES + n] : 0.f;
        tile[ln][b] = v;
    }
    __syncthreads();
    for (int nn = 0; nn < 16; ++nn) {
        int nrel = nn * 4 + sub;
        int n = n0 + nrel;
        if (n < N_NODES) {
            float v = tile[nrel][ln];         // ln = b
            int half = ln >> 5, l32 = ln & 31;
            size_t pos = (size_t)n * 32 + l32;
            (half ? xT1 : xT0)[pos] = v;
            (half ? g1 : g0)[pos] = f2bf(2.f * v);
        }
    }
}

// One launch per step, both halves, XCD-pinned: blockIdx&7 -> XCD (round-robin
// dispatch), XCDs 0-3 own half 0, XCDs 4-7 own half 1. Each XCD's random
// gather then spans only its half's 2.88 MB g buffer -> L2-resident.
// Wave = 2 rows (lanes 0-31 row n0, 32-63 row n0+1).
__global__ __launch_bounds__(256) void step_kernel(const unsigned short* __restrict__ g0In,
                                                   const unsigned short* __restrict__ g1In,
                                                   const float* __restrict__ xT0,
                                                   const float* __restrict__ xT1,
                                                   const unsigned int* __restrict__ pk,
                                                   const float* __restrict__ bias,
                                                   unsigned short* __restrict__ g0Out,
                                                   unsigned short* __restrict__ g1Out,
                                                   int addX) {
    int b    = (int)blockIdx.x;
    int xcd  = b & 7;
    int half = xcd >> 2;
    int sub  = ((b >> 3) << 2) | (xcd & 3);   // 0..5631 within half
    if (sub >= 5625) return;
    int wid  = threadIdx.x >> 6;
    int lane = threadIdx.x & 63;
    int n0 = __builtin_amdgcn_readfirstlane(sub * 8 + wid * 2);
    int rowsel = lane >> 5;
    int l32    = lane & 31;

    const unsigned short* gIn  = half ? g1In  : g0In;
    const float*          xT   = half ? xT1   : xT0;
    unsigned short*       gOut = half ? g1Out : g0Out;

    const unsigned int* p = pk + (size_t)n0 * F_NNZ;   // rows n0, n0+1 contiguous
    float acc = 0.f;
#pragma unroll
    for (int f = 0; f < F_NNZ; ++f) {
        unsigned int e0 = p[f];            // wave-uniform -> scalar load
        unsigned int e1 = p[f + F_NNZ];
        unsigned int e  = rowsel ? e1 : e0;
        int   j = (int)(e & 0xffffu);
        float v = __uint_as_float(e & 0xffff0000u);    // bf16 value in high bits
        acc = fmaf(v, bf2f(gIn[(size_t)j * 32 + l32]), acc);
    }
    int n = n0 + rowsel;
    float tv = fmaxf(acc + bias[n], 0.f);
    size_t o = (size_t)n * 32 + l32;
    float ov = tv;
    if (addX) ov += __builtin_nontemporal_load(&xT[o]);
    __builtin_nontemporal_store(f2bf(ov), &gOut[o]);
}

// Head GEMM partials, no atomics. lane = b (coalesced h-row load), wave w owns
// h in [16w, 16w+16). Partial layout is [h][b] (h*64 + b).
__global__ __launch_bounds__(256) void head_partial4(const unsigned short* __restrict__ h0,
                                                     const unsigned short* __restrict__ h1,
                                                     const float* __restrict__ w1,
                                                     float* __restrict__ partial) {
    int lane = threadIdx.x & 63;   // b
    int w    = threadIdx.x >> 6;   // h-group
    const unsigned short* hh = (lane >> 5) ? h1 : h0;
    int l32  = lane & 31;
    int n0   = blockIdx.x * HCHUNK;
    float acc[16];
#pragma unroll
    for (int k = 0; k < 16; ++k) acc[k] = 0.f;
    for (int i = 0; i < HCHUNK; ++i) {
        int n = n0 + i;
        float hv = bf2f(hh[(size_t)n * 32 + l32]);           // coalesced
        const float* wrow = w1 + (size_t)n * 64 + w * 16;    // wave-uniform
#pragma unroll
        for (int k = 0; k < 16; ++k)
            acc[k] = fmaf(hv, wrow[k], acc[k]);
    }
    float* pp = partial + (size_t)blockIdx.x * 4096;
#pragma unroll
    for (int k = 0; k < 16; ++k)
        pp[(size_t)(w * 16 + k) * 64 + lane] = acc[k];       // [h][b]
}

// hidAcc[t] = sum over chunks of partial[chunk][t]  (layout [h][b] preserved)
__global__ __launch_bounds__(256) void head_reduce(const float* __restrict__ partial,
                                                   float* __restrict__ hidAcc) {
    int t = blockIdx.x * 256 + threadIdx.x;
    float acc = 0.f;
    for (int i = 0; i < NHEADBLK; ++i) acc += partial[(size_t)i * 4096 + t];
    hidAcc[t] = acc;
}

// out[b][c] = b2[c] + sum_h relu(hid[h][b] + b1[h]) * w2[h][c]   (hidAcc is [h][b])
__global__ __launch_bounds__(1024) void head_final(const float* __restrict__ hidAcc,
                                                   const float* __restrict__ b1,
                                                   const float* __restrict__ w2,
                                                   const float* __restrict__ b2,
                                                   float* __restrict__ out) {
    int t = threadIdx.x;
    if (t >= 640) return;
    int b = t / 10, c = t % 10;
    float acc = b2[c];
#pragma unroll
    for (int h = 0; h < 64; ++h) {
        float hv = fmaxf(hidAcc[h * 64 + b] + b1[h], 0.f);   // transposed read
        acc = fmaf(hv, w2[h * 10 + c], acc);
    }
    out[t] = acc;
}

extern "C" void kernel_launch(void* const* d_in, const int* in_sizes, int n_in,
                              void* d_out, int out_size, void* d_ws, size_t ws_size,
                              hipStream_t stream) {
    const float* x      = (const float*)d_in[0];
    const float* values = (const float*)d_in[1];
    const float* bias   = (const float*)d_in[2];
    const float* w1     = (const float*)d_in[3];
    const float* b1     = (const float*)d_in[4];
    const float* w2     = (const float*)d_in[5];
    const float* b2     = (const float*)d_in[6];
    const int*   idx    = (const int*)d_in[7];
    float* out = (float*)d_out;

    size_t perHalfF = (size_t)N_NODES * 32;
    float*          xT0 = (float*)d_ws;                        // 5.76 MB
    float*          xT1 = xT0 + perHalfF;                      // 5.76 MB
    unsigned short* gA0 = (unsigned short*)(xT1 + perHalfF);   // 2.88 MB each
    unsigned short* gB0 = gA0 + perHalfF;
    unsigned short* gA1 = gB0 + perHalfF;
    unsigned short* gB1 = gA1 + perHalfF;
    unsigned int*   pk  = (unsigned int*)(gB1 + perHalfF);     // 5.94 MB
    float*          partial = (float*)(pk + (size_t)N_NODES * F_NNZ);  // 7.37 MB
    float*          hidAcc  = partial + (size_t)NHEADBLK * 4096;       // 16 KB

    pack_kernel<<<(N_NODES * F_NNZ + 255) / 256, 256, 0, stream>>>(idx, values, pk);
    transpose_init<<<(N_NODES + 63) / 64, 256, 0, stream>>>(x, xT0, xT1, gA0, gA1);

    const unsigned short* gin0 = gA0; unsigned short* gout0 = gB0;
    const unsigned short* gin1 = gA1; unsigned short* gout1 = gB1;
    for (int s = 0; s < NUM_STEPS; ++s) {
        int addX = (s < NUM_STEPS - 1) ? 1 : 0;
        step_kernel<<<11264, 256, 0, stream>>>(gin0, gin1, xT0, xT1, pk, bias,
                                               gout0, gout1, addX);
        unsigned short* t0 = (unsigned short*)gin0; gin0 = gout0; gout0 = t0;
        unsigned short* t1 = (unsigned short*)gin1; gin1 = gout1; gout1 = t1;
    }

    head_partial4<<<NHEADBLK, 256, 0, stream>>>(gin0, gin1, w1, partial);
    head_reduce<<<16, 256, 0, stream>>>(partial, hidAcc);
    head_final<<<1, 1024, 0, stream>>>(hidAcc, b1, w2, b2, out);
}